// Round 2
// baseline (233.317 us; speedup 1.0000x reference)
//
#include <hip/hip_runtime.h>
#include <stdint.h>

typedef unsigned short u16;

#define B_    16
#define T_    512
#define H_    384
#define F_    384
#define DMAX_ 8
#define L_    4096     // T_*DMAX_
#define KD    1152     // 3*H_
#define M_    8192     // B_*T_

typedef __bf16 bf16x8 __attribute__((ext_vector_type(8)));
typedef float  f32x4  __attribute__((ext_vector_type(4)));

__device__ __forceinline__ u16 f2b(float f) {
    union { float f; unsigned int i; } v; v.f = f;
    unsigned int x = v.i;
    return (u16)((x + 0x7fffu + ((x >> 16) & 1u)) >> 16);   // RNE fp32->bf16
}

// ---------------- duration scan + token map ----------------
__global__ void k_durmap(const float* __restrict__ td, int* __restrict__ tmap) {
    __shared__ int s[T_];
    int b = blockIdx.x, t = threadIdx.x;
    int d = (int)roundf(expf(td[b * T_ + t]));
    if (d < 0) d = 0; if (d > DMAX_) d = DMAX_;
    int v = d;
    s[t] = v;
    __syncthreads();
    for (int off = 1; off < T_; off <<= 1) {
        int add = (t >= off) ? s[t - off] : 0;
        __syncthreads();
        v += add;
        s[t] = v;
        __syncthreads();
    }
    int end = v, start = end - d;
    for (int i = start; i < end; ++i) tmap[b * L_ + i] = t;
    int total = s[T_ - 1];
    for (int l = total + t; l < L_; l += T_) tmap[b * L_ + l] = -1;
}

// ---------------- length-regulate gather (output 0, fp32 copy) ----------------
__global__ void k_expand(const float* __restrict__ x, const int* __restrict__ tmap,
                         float* __restrict__ out) {
    int v = blockIdx.x * blockDim.x + threadIdx.x;      // B*L*96 float4s
    if (v >= B_ * L_ * 96) return;
    int row = v / 96, c4 = v % 96;
    int b = row >> 12;
    int t = tmap[row];
    uint4 val = make_uint4(0u, 0u, 0u, 0u);
    if (t >= 0) val = *(const uint4*)(x + (size_t)((b << 9) + t) * H_ + c4 * 4);
    *(uint4*)(out + (size_t)row * H_ + c4 * 4) = val;
}

// ---------------- weight repack fp32 w[f][c][kk] -> bf16 Wp[f][kk*H+c] ----------------
__global__ void k_repack(const float* __restrict__ w1, const float* __restrict__ w2,
                         u16* __restrict__ Wp1, u16* __restrict__ Wp2) {
    int i = blockIdx.x * blockDim.x + threadIdx.x;
    const int n = F_ * H_ * 3;
    if (i >= 2 * n) return;
    const float* src = (i < n) ? w1 : w2;
    u16* dst         = (i < n) ? Wp1 : Wp2;
    int j = (i < n) ? i : i - n;
    int f = j / (H_ * 3);
    int rem = j % (H_ * 3);
    int c = rem / 3, kk = rem % 3;
    dst[f * KD + kk * H_ + c] = f2b(src[j]);
}

// ---------------- im2col fp32 x -> bf16 A[bt][kk*H+c] = x[b, t+kk-1, c] ----------------
__global__ void k_im2col(const float* __restrict__ x, u16* __restrict__ A) {
    int v = blockIdx.x * blockDim.x + threadIdx.x;      // M*288 groups of 4 elems
    if (v >= M_ * 288) return;
    int bt = v / 288, r = v % 288;
    int kk = r / 96, c4 = r % 96;
    int b = bt >> 9, t = bt & 511;
    int ts = t + kk - 1;
    u16 o[4] = {0, 0, 0, 0};
    if (ts >= 0 && ts < T_) {
        const float* p = x + (size_t)((b << 9) + ts) * H_ + c4 * 4;
        float4 f = *(const float4*)p;
        o[0] = f2b(f.x); o[1] = f2b(f.y); o[2] = f2b(f.z); o[3] = f2b(f.w);
    }
    *(uint2*)(A + (size_t)bt * KD + kk * H_ + c4 * 4) = *(uint2*)o;
}

// ---------------- MFMA GEMM: C[m][n] = sum_k A[m][k]*Bw[n][k] + bias[n] ----------------
#define BM 128
#define BN 128
#define BK 32
#define LDSS 40   // padded LDS row stride (elements)

__launch_bounds__(256, 2)
__global__ void k_gemm(const u16* __restrict__ A, const u16* __restrict__ Bw,
                       const float* __restrict__ bias, float* __restrict__ C,
                       int M, int N, int K) {
    __shared__ u16 Al[BM * LDSS];
    __shared__ u16 Bl[BN * LDSS];
    int tid = threadIdx.x;
    int m0 = blockIdx.x * BM;
    int n0 = blockIdx.y * BN;
    int w = tid >> 6, lane = tid & 63;
    int quad = lane >> 4, l16 = lane & 15;
    int wm = w & 1, wn = w >> 1;

    f32x4 acc[4][4];
    for (int i = 0; i < 4; ++i)
        for (int j = 0; j < 4; ++j)
            acc[i][j] = f32x4{0.f, 0.f, 0.f, 0.f};

    for (int k0 = 0; k0 < K; k0 += BK) {
        #pragma unroll
        for (int p = 0; p < 2; ++p) {
            int v = tid + p * 256;
            int row = v >> 2, cv = v & 3;
            *(uint4*)&Al[row * LDSS + cv * 8] =
                *(const uint4*)(A + (size_t)(m0 + row) * K + k0 + cv * 8);
            *(uint4*)&Bl[row * LDSS + cv * 8] =
                *(const uint4*)(Bw + (size_t)(n0 + row) * K + k0 + cv * 8);
        }
        __syncthreads();
        bf16x8 af[4], bfr[4];
        #pragma unroll
        for (int i = 0; i < 4; ++i)
            af[i] = *(const bf16x8*)&Al[(wm * 64 + i * 16 + l16) * LDSS + quad * 8];
        #pragma unroll
        for (int j = 0; j < 4; ++j)
            bfr[j] = *(const bf16x8*)&Bl[(wn * 64 + j * 16 + l16) * LDSS + quad * 8];
        #pragma unroll
        for (int i = 0; i < 4; ++i)
            #pragma unroll
            for (int j = 0; j < 4; ++j)
                acc[i][j] = __builtin_amdgcn_mfma_f32_16x16x32_bf16(af[i], bfr[j], acc[i][j], 0, 0, 0);
        __syncthreads();
    }

    for (int i = 0; i < 4; ++i) {
        for (int j = 0; j < 4; ++j) {
            int row = m0 + wm * 64 + i * 16 + quad * 4;
            int col = n0 + wn * 64 + j * 16 + l16;
            float bb = bias[col];
            #pragma unroll
            for (int r = 0; r < 4; ++r)
                C[(size_t)(row + r) * N + col] = acc[i][j][r] + bb;
        }
    }
}

// ---------------- LN + exact GELU, scatter bf16 into im2col buffer for conv2 ----------------
__global__ void k_lngelu(const float* __restrict__ Hin, const float* __restrict__ g,
                         const float* __restrict__ bta, u16* __restrict__ A2) {
    int row = blockIdx.x;          // b*T + t
    int lane = threadIdx.x;        // 64
    int b = row >> 9, t = row & 511;
    const float* hr = Hin + (size_t)row * F_;
    float vals[6];
    float s = 0.f, s2 = 0.f;
    #pragma unroll
    for (int j = 0; j < 6; ++j) {
        float xv = hr[lane + j * 64];
        vals[j] = xv; s += xv; s2 += xv * xv;
    }
    #pragma unroll
    for (int off = 32; off; off >>= 1) { s += __shfl_down(s, off); s2 += __shfl_down(s2, off); }
    s = __shfl(s, 0); s2 = __shfl(s2, 0);
    float mean = s * (1.f / F_);
    float var  = s2 * (1.f / F_) - mean * mean;
    float rstd = rsqrtf(var + 1e-5f);
    #pragma unroll
    for (int j = 0; j < 6; ++j) {
        int c = lane + j * 64;
        float y  = (vals[j] - mean) * rstd * g[c] + bta[c];
        float gl = 0.5f * y * (1.f + erff(y * 0.70710678118654752f));
        u16 ub = f2b(gl);
        #pragma unroll
        for (int kk = 0; kk < 3; ++kk) {
            int t2 = t + 1 - kk;
            if (t2 >= 0 && t2 < T_)
                A2[(size_t)((b << 9) + t2) * KD + kk * H_ + c] = ub;
        }
    }
    if (t == 0)
        for (int j = 0; j < 6; ++j) A2[(size_t)row * KD + lane + j * 64] = 0;
    if (t == T_ - 1)
        for (int j = 0; j < 6; ++j) A2[(size_t)row * KD + 2 * H_ + lane + j * 64] = 0;
}

// ---------------- LN + GELU + dot(lin_w) + ReLU -> length (output 1, fp32) ----------------
__global__ void k_len(const float* __restrict__ Hin, const float* __restrict__ g,
                      const float* __restrict__ bta, const float* __restrict__ lw,
                      const float* __restrict__ lb, float* __restrict__ lenout) {
    int row = blockIdx.x;
    int lane = threadIdx.x;
    const float* hr = Hin + (size_t)row * F_;
    float vals[6];
    float s = 0.f, s2 = 0.f;
    #pragma unroll
    for (int j = 0; j < 6; ++j) {
        float xv = hr[lane + j * 64];
        vals[j] = xv; s += xv; s2 += xv * xv;
    }
    #pragma unroll
    for (int off = 32; off; off >>= 1) { s += __shfl_down(s, off); s2 += __shfl_down(s2, off); }
    s = __shfl(s, 0); s2 = __shfl(s2, 0);
    float mean = s * (1.f / F_);
    float var  = s2 * (1.f / F_) - mean * mean;
    float rstd = rsqrtf(var + 1e-5f);
    float dot = 0.f;
    #pragma unroll
    for (int j = 0; j < 6; ++j) {
        int c = lane + j * 64;
        float y  = (vals[j] - mean) * rstd * g[c] + bta[c];
        float gl = 0.5f * y * (1.f + erff(y * 0.70710678118654752f));
        dot += gl * lw[c];
    }
    #pragma unroll
    for (int off = 32; off; off >>= 1) dot += __shfl_down(dot, off);
    if (lane == 0) {
        float r = dot + lb[0];
        lenout[row] = fmaxf(r, 0.f);
    }
}

extern "C" void kernel_launch(void* const* d_in, const int* in_sizes, int n_in,
                              void* d_out, int out_size, void* d_ws, size_t ws_size,
                              hipStream_t stream) {
    const float* x   = (const float*)d_in[0];
    const float* td  = (const float*)d_in[1];
    const float* w1  = (const float*)d_in[2];
    const float* b1  = (const float*)d_in[3];
    const float* g1  = (const float*)d_in[4];
    const float* be1 = (const float*)d_in[5];
    const float* w2  = (const float*)d_in[6];
    const float* b2  = (const float*)d_in[7];
    const float* g2  = (const float*)d_in[8];
    const float* be2 = (const float*)d_in[9];
    const float* lw  = (const float*)d_in[10];
    const float* lb  = (const float*)d_in[11];

    float* out0 = (float*)d_out;                     // [B, L, H] fp32
    float* out1 = out0 + (size_t)B_ * L_ * H_;       // [B, T] fp32

    char* ws = (char*)d_ws;
    size_t off = 0;
    auto carve = [&](size_t bytes) -> void* {
        void* p = ws + off;
        off = (off + bytes + 255) & ~(size_t)255;
        return p;
    };
    int*  tmap = (int*)carve((size_t)B_ * L_ * sizeof(int));
    u16*  Wp1  = (u16*)carve((size_t)F_ * KD * sizeof(u16));
    u16*  Wp2  = (u16*)carve((size_t)F_ * KD * sizeof(u16));
    u16*  Aim  = (u16*)carve((size_t)M_ * KD * sizeof(u16));
    float* Hbuf = (float*)carve((size_t)M_ * F_ * sizeof(float));

    // length regulation path
    k_durmap<<<B_, T_, 0, stream>>>(td, tmap);
    k_expand<<<(B_ * L_ * 96 + 255) / 256, 256, 0, stream>>>(x, tmap, out0);

    // predictor path
    k_repack<<<(2 * F_ * H_ * 3 + 255) / 256, 256, 0, stream>>>(w1, w2, Wp1, Wp2);
    k_im2col<<<(M_ * 288 + 255) / 256, 256, 0, stream>>>(x, Aim);
    k_gemm<<<dim3(M_ / BM, F_ / BN), 256, 0, stream>>>(Aim, Wp1, b1, Hbuf, M_, F_, KD);
    k_lngelu<<<M_, 64, 0, stream>>>(Hbuf, g1, be1, Aim);
    k_gemm<<<dim3(M_ / BM, F_ / BN), 256, 0, stream>>>(Aim, Wp2, b2, Hbuf, M_, F_, KD);
    k_len<<<M_, 64, 0, stream>>>(Hbuf, g2, be2, lw, lb, out1);
}

// Round 3
// 212.041 us; speedup vs baseline: 1.1003x; 1.1003x over previous
//
#include <hip/hip_runtime.h>
#include <stdint.h>

typedef unsigned short u16;
typedef unsigned int   u32;

#define B_    16
#define T_    512
#define H_    384
#define F_    384
#define DMAX_ 8
#define L_    4096     // T_*DMAX_
#define KD    1152     // 3*H_
#define M_    8192     // B_*T_

typedef __bf16 bf16x8 __attribute__((ext_vector_type(8)));
typedef float  f32x4  __attribute__((ext_vector_type(4)));

typedef __attribute__((address_space(1))) u32 gu32;
typedef __attribute__((address_space(3))) u32 lu32;

__device__ __forceinline__ void dma16(const void* g, void* l) {
    __builtin_amdgcn_global_load_lds((gu32*)(uintptr_t)g, (lu32*)(u32)(uintptr_t)l, 16, 0, 0);
}

__device__ __forceinline__ u16 f2b(float f) {
    union { float f; u32 i; } v; v.f = f;
    u32 x = v.i;
    return (u16)((x + 0x7fffu + ((x >> 16) & 1u)) >> 16);   // RNE fp32->bf16
}

// ---------------- duration scan + token map ----------------
__global__ void k_durmap(const float* __restrict__ td, int* __restrict__ tmap) {
    __shared__ int s[T_];
    int b = blockIdx.x, t = threadIdx.x;
    int d = (int)roundf(expf(td[b * T_ + t]));
    if (d < 0) d = 0; if (d > DMAX_) d = DMAX_;
    int v = d;
    s[t] = v;
    __syncthreads();
    for (int off = 1; off < T_; off <<= 1) {
        int add = (t >= off) ? s[t - off] : 0;
        __syncthreads();
        v += add;
        s[t] = v;
        __syncthreads();
    }
    int end = v, start = end - d;
    for (int i = start; i < end; ++i) tmap[b * L_ + i] = t;
    int total = s[T_ - 1];
    for (int l = total + t; l < L_; l += T_) tmap[b * L_ + l] = -1;
}

// ---------------- length-regulate gather (output 0, fp32 copy) ----------------
__global__ void k_expand(const float* __restrict__ x, const int* __restrict__ tmap,
                         float* __restrict__ out) {
    int v = blockIdx.x * blockDim.x + threadIdx.x;      // B*L*96 float4s
    if (v >= B_ * L_ * 96) return;
    int row = v / 96, c4 = v % 96;
    int b = row >> 12;
    int t = tmap[row];
    uint4 val = make_uint4(0u, 0u, 0u, 0u);
    if (t >= 0) val = *(const uint4*)(x + (size_t)((b << 9) + t) * H_ + c4 * 4);
    *(uint4*)(out + (size_t)row * H_ + c4 * 4) = val;
}

// ---------------- x fp32 -> bf16 compact [M][H] ----------------
__global__ void k_xcast(const float* __restrict__ x, u16* __restrict__ xb) {
    int v = blockIdx.x * blockDim.x + threadIdx.x;      // M*96 float4 groups
    if (v >= M_ * 96) return;
    float4 f = *(const float4*)(x + (size_t)v * 4);
    u16 o[4] = { f2b(f.x), f2b(f.y), f2b(f.z), f2b(f.w) };
    *(uint2*)(xb + (size_t)v * 4) = *(uint2*)o;
}

// ---------------- weight repack fp32 w[f][c][kk] -> bf16 Wp[f][kk*H+c]; zero page ----------------
__global__ void k_repack(const float* __restrict__ w1, const float* __restrict__ w2,
                         u16* __restrict__ Wp1, u16* __restrict__ Wp2,
                         u16* __restrict__ zp) {
    int i = blockIdx.x * blockDim.x + threadIdx.x;
    if (i < 128) zp[i] = 0;
    const int n = F_ * H_ * 3;
    if (i >= 2 * n) return;
    const float* src = (i < n) ? w1 : w2;
    u16* dst         = (i < n) ? Wp1 : Wp2;
    int j = (i < n) ? i : i - n;
    int f = j / (H_ * 3);
    int rem = j % (H_ * 3);
    int c = rem / 3, kk = rem % 3;
    dst[f * KD + kk * H_ + c] = f2b(src[j]);
}

// ---------------- fused im2col MFMA GEMM ----------------
// C[bt][f] = sum_{kk,c} src[b, t+kk-1, c] * Wp[f][kk*H+c] + bias[f]
// src: compact bf16 [M][H]; boundary rows -> zp. BM=64, BN=128, BK=32.
// LDS: 768 chunks of 16B; chunk gc holds (row=gc>>2, colgroup q=(gc&3)^((row>>1)&3)).
// A = chunks [0,256), B = chunks [256,768).
__launch_bounds__(256, 4)
__global__ void k_gemm(const u16* __restrict__ src, const u16* __restrict__ Wp,
                       const float* __restrict__ bias, float* __restrict__ C,
                       const u16* __restrict__ zp) {
    __shared__ u16 smem[768 * 8];
    int tid = threadIdx.x;
    int w = tid >> 6, lane = tid & 63;
    int quad = lane >> 4, l16 = lane & 15;
    int m0 = blockIdx.x * 64;
    int n0 = blockIdx.y * 128;

    // --- staging lane setup (3 dma16 per thread per K-step) ---
    int idx0 = w * 64 + lane;                 // A chunk id [0,256)
    int rowA = idx0 >> 2;
    int qA   = (idx0 & 3) ^ ((rowA >> 1) & 3);
    int arow = m0 + rowA;
    int bB   = arow >> 9, tt = arow & 511;
    int rowB = idx0 >> 2;                     // B rows [0,64) and +64
    int qB   = (idx0 & 3) ^ ((rowB >> 1) & 3);
    const u16* srcB1 = Wp + (size_t)(n0 + rowB) * KD + qB * 8;
    const u16* srcB2 = Wp + (size_t)(n0 + rowB + 64) * KD + qB * 8;
    u16* ldsA  = smem + (size_t)w * 512;             // w*64 chunks * 8 elems
    u16* ldsB1 = smem + 2048 + (size_t)w * 512;
    u16* ldsB2 = smem + 4096 + (size_t)w * 512;

    // --- MFMA frag addresses (swizzled) ---
    int wm = w & 1, wn = w >> 1;
    const u16* aptr[2];
    const u16* bptr[4];
    #pragma unroll
    for (int i = 0; i < 2; ++i) {
        int row = wm * 32 + i * 16 + l16;
        aptr[i] = smem + (((row << 2) | (quad ^ ((row >> 1) & 3))) << 3);
    }
    #pragma unroll
    for (int j = 0; j < 4; ++j) {
        int row = wn * 64 + j * 16 + l16;
        bptr[j] = smem + ((256 + ((row << 2) | (quad ^ ((row >> 1) & 3)))) << 3);
    }

    f32x4 acc[2][4];
    #pragma unroll
    for (int i = 0; i < 2; ++i)
        #pragma unroll
        for (int j = 0; j < 4; ++j)
            acc[i][j] = f32x4{0.f, 0.f, 0.f, 0.f};

    for (int k0 = 0; k0 < KD; k0 += 32) {
        // A: shifted im2col source
        int kg = k0 + qA * 8;
        int kk = (kg >= 768) ? 2 : ((kg >= 384) ? 1 : 0);
        int c  = kg - kk * 384;
        int ts = tt + kk - 1;
        const u16* sA = (ts >= 0 && ts < T_) ? (src + (size_t)((bB << 9) + ts) * H_ + c) : zp;
        dma16(sA, ldsA);
        dma16(srcB1 + k0, ldsB1);
        dma16(srcB2 + k0, ldsB2);
        __syncthreads();

        bf16x8 af[2], bfr[4];
        #pragma unroll
        for (int i = 0; i < 2; ++i) af[i]  = *(const bf16x8*)aptr[i];
        #pragma unroll
        for (int j = 0; j < 4; ++j) bfr[j] = *(const bf16x8*)bptr[j];
        #pragma unroll
        for (int i = 0; i < 2; ++i)
            #pragma unroll
            for (int j = 0; j < 4; ++j)
                acc[i][j] = __builtin_amdgcn_mfma_f32_16x16x32_bf16(af[i], bfr[j], acc[i][j], 0, 0, 0);
        __syncthreads();
    }

    #pragma unroll
    for (int i = 0; i < 2; ++i) {
        #pragma unroll
        for (int j = 0; j < 4; ++j) {
            int row = m0 + wm * 32 + i * 16 + quad * 4;
            int col = n0 + wn * 64 + j * 16 + l16;
            float bb = bias[col];
            #pragma unroll
            for (int r = 0; r < 4; ++r)
                C[(size_t)(row + r) * F_ + col] = acc[i][j][r] + bb;
        }
    }
}

// ---------------- LN + exact GELU -> compact bf16 G[M][F] ----------------
__global__ void k_lngelu(const float* __restrict__ Hin, const float* __restrict__ g,
                         const float* __restrict__ bta, u16* __restrict__ G) {
    int row = blockIdx.x;          // b*T + t
    int lane = threadIdx.x;        // 64
    const float* hr = Hin + (size_t)row * F_;
    float vals[6];
    float s = 0.f, s2 = 0.f;
    #pragma unroll
    for (int j = 0; j < 6; ++j) {
        float xv = hr[lane + j * 64];
        vals[j] = xv; s += xv; s2 += xv * xv;
    }
    #pragma unroll
    for (int off = 32; off; off >>= 1) { s += __shfl_down(s, off); s2 += __shfl_down(s2, off); }
    s = __shfl(s, 0); s2 = __shfl(s2, 0);
    float mean = s * (1.f / F_);
    float var  = s2 * (1.f / F_) - mean * mean;
    float rstd = rsqrtf(var + 1e-5f);
    #pragma unroll
    for (int j = 0; j < 6; ++j) {
        int c = lane + j * 64;
        float y  = (vals[j] - mean) * rstd * g[c] + bta[c];
        float gl = 0.5f * y * (1.f + erff(y * 0.70710678118654752f));
        G[(size_t)row * F_ + c] = f2b(gl);
    }
}

// ---------------- LN + GELU + dot(lin_w) + ReLU -> length (output 1, fp32) ----------------
__global__ void k_len(const float* __restrict__ Hin, const float* __restrict__ g,
                      const float* __restrict__ bta, const float* __restrict__ lw,
                      const float* __restrict__ lb, float* __restrict__ lenout) {
    int row = blockIdx.x;
    int lane = threadIdx.x;
    const float* hr = Hin + (size_t)row * F_;
    float vals[6];
    float s = 0.f, s2 = 0.f;
    #pragma unroll
    for (int j = 0; j < 6; ++j) {
        float xv = hr[lane + j * 64];
        vals[j] = xv; s += xv; s2 += xv * xv;
    }
    #pragma unroll
    for (int off = 32; off; off >>= 1) { s += __shfl_down(s, off); s2 += __shfl_down(s2, off); }
    s = __shfl(s, 0); s2 = __shfl(s2, 0);
    float mean = s * (1.f / F_);
    float var  = s2 * (1.f / F_) - mean * mean;
    float rstd = rsqrtf(var + 1e-5f);
    float dot = 0.f;
    #pragma unroll
    for (int j = 0; j < 6; ++j) {
        int c = lane + j * 64;
        float y  = (vals[j] - mean) * rstd * g[c] + bta[c];
        float gl = 0.5f * y * (1.f + erff(y * 0.70710678118654752f));
        dot += gl * lw[c];
    }
    #pragma unroll
    for (int off = 32; off; off >>= 1) dot += __shfl_down(dot, off);
    if (lane == 0) {
        float r = dot + lb[0];
        lenout[row] = fmaxf(r, 0.f);
    }
}

extern "C" void kernel_launch(void* const* d_in, const int* in_sizes, int n_in,
                              void* d_out, int out_size, void* d_ws, size_t ws_size,
                              hipStream_t stream) {
    const float* x   = (const float*)d_in[0];
    const float* td  = (const float*)d_in[1];
    const float* w1  = (const float*)d_in[2];
    const float* b1  = (const float*)d_in[3];
    const float* g1  = (const float*)d_in[4];
    const float* be1 = (const float*)d_in[5];
    const float* w2  = (const float*)d_in[6];
    const float* b2  = (const float*)d_in[7];
    const float* g2  = (const float*)d_in[8];
    const float* be2 = (const float*)d_in[9];
    const float* lw  = (const float*)d_in[10];
    const float* lb  = (const float*)d_in[11];

    float* out0 = (float*)d_out;                     // [B, L, H] fp32
    float* out1 = out0 + (size_t)B_ * L_ * H_;       // [B, T] fp32

    char* ws = (char*)d_ws;
    size_t off = 0;
    auto carve = [&](size_t bytes) -> void* {
        void* p = ws + off;
        off = (off + bytes + 255) & ~(size_t)255;
        return p;
    };
    int*  tmap  = (int*)carve((size_t)B_ * L_ * sizeof(int));
    u16*  Wp1   = (u16*)carve((size_t)F_ * KD * sizeof(u16));
    u16*  Wp2   = (u16*)carve((size_t)F_ * KD * sizeof(u16));
    u16*  xb    = (u16*)carve((size_t)M_ * H_ * sizeof(u16));
    u16*  G     = (u16*)carve((size_t)M_ * F_ * sizeof(u16));
    u16*  zp    = (u16*)carve(256);
    float* Hbuf = (float*)carve((size_t)M_ * F_ * sizeof(float));

    // length regulation path
    k_durmap<<<B_, T_, 0, stream>>>(td, tmap);
    k_expand<<<(B_ * L_ * 96 + 255) / 256, 256, 0, stream>>>(x, tmap, out0);

    // predictor path
    k_repack<<<(2 * F_ * H_ * 3 + 255) / 256, 256, 0, stream>>>(w1, w2, Wp1, Wp2, zp);
    k_xcast<<<(M_ * 96 + 255) / 256, 256, 0, stream>>>(x, xb);
    k_gemm<<<dim3(M_ / 64, 3), 256, 0, stream>>>(xb, Wp1, b1, Hbuf, zp);
    k_lngelu<<<M_, 64, 0, stream>>>(Hbuf, g1, be1, G);
    k_gemm<<<dim3(M_ / 64, 3), 256, 0, stream>>>(G, Wp2, b2, Hbuf, zp);
    k_len<<<M_, 64, 0, stream>>>(Hbuf, g2, be2, lw, lb, out1);
}

// Round 4
// 197.859 us; speedup vs baseline: 1.1792x; 1.0717x over previous
//
#include <hip/hip_runtime.h>
#include <stdint.h>

typedef unsigned short u16;
typedef unsigned int   u32;

#define B_    16
#define T_    512
#define H_    384
#define F_    384
#define DMAX_ 8
#define L_    4096     // T_*DMAX_
#define KD    1152     // 3*H_
#define M_    8192     // B_*T_

typedef __bf16 bf16x8 __attribute__((ext_vector_type(8)));
typedef float  f32x4  __attribute__((ext_vector_type(4)));

typedef __attribute__((address_space(1))) u32 gu32;
typedef __attribute__((address_space(3))) u32 lu32;

__device__ __forceinline__ void dma16(const void* g, void* l) {
    __builtin_amdgcn_global_load_lds((gu32*)(uintptr_t)g, (lu32*)(u32)(uintptr_t)l, 16, 0, 0);
}

__device__ __forceinline__ u16 f2b(float f) {
    union { float f; u32 i; } v; v.f = f;
    u32 x = v.i;
    return (u16)((x + 0x7fffu + ((x >> 16) & 1u)) >> 16);   // RNE fp32->bf16
}
__device__ __forceinline__ float b2f(u16 u) {
    union { u32 i; float f; } v; v.i = ((u32)u) << 16; return v.f;
}

// ---------------- duration scan + token map ----------------
__global__ void k_durmap(const float* __restrict__ td, int* __restrict__ tmap) {
    __shared__ int s[T_];
    int b = blockIdx.x, t = threadIdx.x;
    int d = (int)roundf(expf(td[b * T_ + t]));
    if (d < 0) d = 0; if (d > DMAX_) d = DMAX_;
    int v = d;
    s[t] = v;
    __syncthreads();
    for (int off = 1; off < T_; off <<= 1) {
        int add = (t >= off) ? s[t - off] : 0;
        __syncthreads();
        v += add;
        s[t] = v;
        __syncthreads();
    }
    int end = v, start = end - d;
    for (int i = start; i < end; ++i) tmap[b * L_ + i] = t;
    int total = s[T_ - 1];
    for (int l = total + t; l < L_; l += T_) tmap[b * L_ + l] = -1;
}

// ---------------- length-regulate gather (output 0, fp32 copy) ----------------
__global__ void k_expand(const float* __restrict__ x, const int* __restrict__ tmap,
                         float* __restrict__ out) {
    int v = blockIdx.x * blockDim.x + threadIdx.x;      // B*L*96 float4s
    if (v >= B_ * L_ * 96) return;
    int row = v / 96, c4 = v % 96;
    int b = row >> 12;
    int t = tmap[row];
    uint4 val = make_uint4(0u, 0u, 0u, 0u);
    if (t >= 0) val = *(const uint4*)(x + (size_t)((b << 9) + t) * H_ + c4 * 4);
    *(uint4*)(out + (size_t)row * H_ + c4 * 4) = val;
}

// ---------------- x fp32 -> bf16 compact [M][H] ----------------
__global__ void k_xcast(const float* __restrict__ x, u16* __restrict__ xb) {
    int v = blockIdx.x * blockDim.x + threadIdx.x;      // M*96 float4 groups
    if (v >= M_ * 96) return;
    float4 f = *(const float4*)(x + (size_t)v * 4);
    u16 o[4] = { f2b(f.x), f2b(f.y), f2b(f.z), f2b(f.w) };
    *(uint2*)(xb + (size_t)v * 4) = *(uint2*)o;
}

// ---------------- weight repack fp32 w[f][c][kk] -> bf16 Wp[f][kk*H+c]; zero page ----------------
__global__ void k_repack(const float* __restrict__ w1, const float* __restrict__ w2,
                         u16* __restrict__ Wp1, u16* __restrict__ Wp2,
                         u16* __restrict__ zp) {
    int i = blockIdx.x * blockDim.x + threadIdx.x;
    if (i < 512) zp[i] = 0;
    const int n = F_ * H_ * 3;
    if (i >= 2 * n) return;
    const float* src = (i < n) ? w1 : w2;
    u16* dst         = (i < n) ? Wp1 : Wp2;
    int j = (i < n) ? i : i - n;
    int f = j / (H_ * 3);
    int rem = j % (H_ * 3);
    int c = rem / 3, kk = rem % 3;
    dst[f * KD + kk * H_ + c] = f2b(src[j]);
}

// ---------------- fused im2col MFMA GEMM ----------------
// Hb[bt][f] = bf16( sum_{kk,c} src[b, t+kk-1, c] * Wp[f][kk*H+c] + bias[f] )
// BM=32, BN=128, BK=64; grid (256,3) = 768 blocks (3/CU resident).
// LDS: 1280 chunks of 16B. A = chunks [0,256): (row=gc>>3, q_phys=gc&7),
// B = chunks [256,1280). Swizzle: q_phys = q_log ^ (row&7)  (conflict-free b128).
__launch_bounds__(256, 3)
__global__ void k_gemm(const u16* __restrict__ src, const u16* __restrict__ Wp,
                       const float* __restrict__ bias, u16* __restrict__ Hb,
                       const u16* __restrict__ zp) {
    __shared__ u16 smem[1280 * 8];
    int tid = threadIdx.x;
    int w = tid >> 6, lane = tid & 63;
    int quad = lane >> 4, l16 = lane & 15;
    int m0 = blockIdx.x * 32;
    int n0 = blockIdx.y * 128;

    // --- staging setup: 5 dma16/thread/step ---
    // p=0: A chunk gc=tid in [0,256)
    int rowA = tid >> 3;
    int qlA  = (tid & 7) ^ (rowA & 7);
    int coffA = qlA * 8;
    int arow = m0 + rowA;
    int bB = arow >> 9, tt = arow & 511;
    const u16* abase[3];
    #pragma unroll
    for (int kk = 0; kk < 3; ++kk) {
        int ts = tt + kk - 1;
        abase[kk] = (ts >= 0 && ts < T_) ? (src + (size_t)((bB << 9) + ts) * H_ + coffA)
                                         : (zp + coffA);
    }
    u16* destA = smem + (size_t)w * 512;              // chunk w*64
    // p=1..4: B chunk bc = tid + (p-1)*256
    const u16* bsrc[4];
    u16* destB[4];
    #pragma unroll
    for (int p = 0; p < 4; ++p) {
        int bc = tid + p * 256;
        int rowB = bc >> 3;
        int qlB  = (bc & 7) ^ (rowB & 7);
        bsrc[p]  = Wp + (size_t)(n0 + rowB) * KD + qlB * 8;
        destB[p] = smem + (size_t)((p + 1) * 256 + w * 64) * 8;
    }

    // --- MFMA fragment LDS addresses (swizzled, constant across steps) ---
    const u16* aptr[2][2];
    const u16* bptr[2][2];
    #pragma unroll
    for (int i = 0; i < 2; ++i)
        #pragma unroll
        for (int kv = 0; kv < 2; ++kv) {
            int row = i * 16 + l16;
            aptr[i][kv] = smem + (size_t)((row << 3) | ((kv * 4 + quad) ^ (row & 7))) * 8;
        }
    #pragma unroll
    for (int j = 0; j < 2; ++j)
        #pragma unroll
        for (int kv = 0; kv < 2; ++kv) {
            int row = w * 32 + j * 16 + l16;
            bptr[j][kv] = smem + (size_t)(256 + ((row << 3) | ((kv * 4 + quad) ^ (row & 7)))) * 8;
        }

    f32x4 acc[2][2];
    #pragma unroll
    for (int i = 0; i < 2; ++i)
        #pragma unroll
        for (int j = 0; j < 2; ++j)
            acc[i][j] = f32x4{0.f, 0.f, 0.f, 0.f};

    #pragma unroll
    for (int kk = 0; kk < 3; ++kk) {
        #pragma unroll
        for (int s = 0; s < 6; ++s) {
            int k0 = kk * 384 + s * 64;
            dma16(abase[kk] + s * 64, destA);
            #pragma unroll
            for (int p = 0; p < 4; ++p) dma16(bsrc[p] + k0, destB[p]);
            __syncthreads();

            bf16x8 af[2][2], bf[2][2];
            #pragma unroll
            for (int i = 0; i < 2; ++i)
                #pragma unroll
                for (int kv = 0; kv < 2; ++kv) af[i][kv] = *(const bf16x8*)aptr[i][kv];
            #pragma unroll
            for (int j = 0; j < 2; ++j)
                #pragma unroll
                for (int kv = 0; kv < 2; ++kv) bf[j][kv] = *(const bf16x8*)bptr[j][kv];
            #pragma unroll
            for (int kv = 0; kv < 2; ++kv)
                #pragma unroll
                for (int i = 0; i < 2; ++i)
                    #pragma unroll
                    for (int j = 0; j < 2; ++j)
                        acc[i][j] = __builtin_amdgcn_mfma_f32_16x16x32_bf16(af[i][kv], bf[j][kv], acc[i][j], 0, 0, 0);
            __syncthreads();
        }
    }

    #pragma unroll
    for (int i = 0; i < 2; ++i) {
        #pragma unroll
        for (int j = 0; j < 2; ++j) {
            int row = m0 + i * 16 + quad * 4;
            int col = n0 + w * 32 + j * 16 + l16;
            float bb = bias[col];
            #pragma unroll
            for (int r = 0; r < 4; ++r)
                Hb[(size_t)(row + r) * F_ + col] = f2b(acc[i][j][r] + bb);
        }
    }
}

// ---------------- LN + exact GELU -> compact bf16 G[M][F] ----------------
__global__ void k_lngelu(const u16* __restrict__ Hin, const float* __restrict__ g,
                         const float* __restrict__ bta, u16* __restrict__ G) {
    int row = blockIdx.x;          // b*T + t
    int lane = threadIdx.x;        // 64
    const u16* hr = Hin + (size_t)row * F_;
    float vals[6];
    float s = 0.f, s2 = 0.f;
    #pragma unroll
    for (int j = 0; j < 6; ++j) {
        float xv = b2f(hr[lane + j * 64]);
        vals[j] = xv; s += xv; s2 += xv * xv;
    }
    #pragma unroll
    for (int off = 32; off; off >>= 1) { s += __shfl_down(s, off); s2 += __shfl_down(s2, off); }
    s = __shfl(s, 0); s2 = __shfl(s2, 0);
    float mean = s * (1.f / F_);
    float var  = s2 * (1.f / F_) - mean * mean;
    float rstd = rsqrtf(var + 1e-5f);
    #pragma unroll
    for (int j = 0; j < 6; ++j) {
        int c = lane + j * 64;
        float y  = (vals[j] - mean) * rstd * g[c] + bta[c];
        float gl = 0.5f * y * (1.f + erff(y * 0.70710678118654752f));
        G[(size_t)row * F_ + c] = f2b(gl);
    }
}

// ---------------- LN + GELU + dot(lin_w) + ReLU -> length (output 1, fp32) ----------------
__global__ void k_len(const u16* __restrict__ Hin, const float* __restrict__ g,
                      const float* __restrict__ bta, const float* __restrict__ lw,
                      const float* __restrict__ lb, float* __restrict__ lenout) {
    int row = blockIdx.x;
    int lane = threadIdx.x;
    const u16* hr = Hin + (size_t)row * F_;
    float vals[6];
    float s = 0.f, s2 = 0.f;
    #pragma unroll
    for (int j = 0; j < 6; ++j) {
        float xv = b2f(hr[lane + j * 64]);
        vals[j] = xv; s += xv; s2 += xv * xv;
    }
    #pragma unroll
    for (int off = 32; off; off >>= 1) { s += __shfl_down(s, off); s2 += __shfl_down(s2, off); }
    s = __shfl(s, 0); s2 = __shfl(s2, 0);
    float mean = s * (1.f / F_);
    float var  = s2 * (1.f / F_) - mean * mean;
    float rstd = rsqrtf(var + 1e-5f);
    float dot = 0.f;
    #pragma unroll
    for (int j = 0; j < 6; ++j) {
        int c = lane + j * 64;
        float y  = (vals[j] - mean) * rstd * g[c] + bta[c];
        float gl = 0.5f * y * (1.f + erff(y * 0.70710678118654752f));
        dot += gl * lw[c];
    }
    #pragma unroll
    for (int off = 32; off; off >>= 1) dot += __shfl_down(dot, off);
    if (lane == 0) {
        float r = dot + lb[0];
        lenout[row] = fmaxf(r, 0.f);
    }
}

extern "C" void kernel_launch(void* const* d_in, const int* in_sizes, int n_in,
                              void* d_out, int out_size, void* d_ws, size_t ws_size,
                              hipStream_t stream) {
    const float* x   = (const float*)d_in[0];
    const float* td  = (const float*)d_in[1];
    const float* w1  = (const float*)d_in[2];
    const float* b1  = (const float*)d_in[3];
    const float* g1  = (const float*)d_in[4];
    const float* be1 = (const float*)d_in[5];
    const float* w2  = (const float*)d_in[6];
    const float* b2  = (const float*)d_in[7];
    const float* g2  = (const float*)d_in[8];
    const float* be2 = (const float*)d_in[9];
    const float* lw  = (const float*)d_in[10];
    const float* lb  = (const float*)d_in[11];

    float* out0 = (float*)d_out;                     // [B, L, H] fp32
    float* out1 = out0 + (size_t)B_ * L_ * H_;       // [B, T] fp32

    char* ws = (char*)d_ws;
    size_t off = 0;
    auto carve = [&](size_t bytes) -> void* {
        void* p = ws + off;
        off = (off + bytes + 255) & ~(size_t)255;
        return p;
    };
    int*  tmap = (int*)carve((size_t)B_ * L_ * sizeof(int));
    u16*  Wp1  = (u16*)carve((size_t)F_ * KD * sizeof(u16));
    u16*  Wp2  = (u16*)carve((size_t)F_ * KD * sizeof(u16));
    u16*  xb   = (u16*)carve((size_t)M_ * H_ * sizeof(u16));
    u16*  G    = (u16*)carve((size_t)M_ * F_ * sizeof(u16));
    u16*  zp   = (u16*)carve(1024);
    u16*  Hb   = (u16*)carve((size_t)M_ * F_ * sizeof(u16));

    // length regulation path
    k_durmap<<<B_, T_, 0, stream>>>(td, tmap);
    k_expand<<<(B_ * L_ * 96 + 255) / 256, 256, 0, stream>>>(x, tmap, out0);

    // predictor path
    k_repack<<<(2 * F_ * H_ * 3 + 255) / 256, 256, 0, stream>>>(w1, w2, Wp1, Wp2, zp);
    k_xcast<<<(M_ * 96 + 255) / 256, 256, 0, stream>>>(x, xb);
    k_gemm<<<dim3(M_ / 32, 3), 256, 0, stream>>>(xb, Wp1, b1, Hb, zp);
    k_lngelu<<<M_, 64, 0, stream>>>(Hb, g1, be1, G);
    k_gemm<<<dim3(M_ / 32, 3), 256, 0, stream>>>(G, Wp2, b2, Hb, zp);
    k_len<<<M_, 64, 0, stream>>>(Hb, g2, be2, lw, lb, out1);
}